// Round 2
// baseline (2587.759 us; speedup 1.0000x reference)
//
#include <hip/hip_runtime.h>
#include <hip/hip_bf16.h>
#include <math.h>

// Problem constants (fixed by the reference)
#define N_TOK 4096
#define DIM   1024
#define NEXP  16
#define HID   1536
#define TOPK2 2
#define NASSIGN (N_TOK * TOPK2)   // 8192

#define BM 64
#define BN 64
#define BK 16

// ---------------- Router: one block per token ----------------
__global__ void router_kernel(const float* __restrict__ x,
                              const float* __restrict__ rw,
                              int* __restrict__ counts, float* __restrict__ gsum,
                              int* __restrict__ idx, float* __restrict__ gate) {
    int n = blockIdx.x;
    __shared__ float xs[DIM];
    __shared__ float lg[NEXP];
    const float* xr = x + (size_t)n * DIM;
    for (int d = threadIdx.x; d < DIM; d += 256) xs[d] = xr[d];
    __syncthreads();
    int wave = threadIdx.x >> 6, lane = threadIdx.x & 63;
    for (int e = wave; e < NEXP; e += 4) {
        const float* wr = rw + (size_t)e * DIM;
        float s = 0.f;
        for (int d = lane; d < DIM; d += 64) s += xs[d] * wr[d];
        #pragma unroll
        for (int off = 32; off > 0; off >>= 1) s += __shfl_down(s, off, 64);
        if (lane == 0) lg[e] = s;
    }
    __syncthreads();
    if (threadIdx.x == 0) {
        float v0 = -3.402823466e+38f, v1 = -3.402823466e+38f;
        int i0 = 0, i1 = 0;
        for (int e = 0; e < NEXP; e++) {
            float v = lg[e];
            if (v > v0) { v1 = v0; i1 = i0; v0 = v; i0 = e; }
            else if (v > v1) { v1 = v; i1 = e; }
        }
        float e1 = expf(v1 - v0);
        float inv = 1.f / (1.f + e1);
        float g0 = inv, g1 = e1 * inv;
        idx[2 * n] = i0; idx[2 * n + 1] = i1;
        gate[2 * n] = g0; gate[2 * n + 1] = g1;
        atomicAdd(&counts[i0], 1); atomicAdd(&counts[i1], 1);
        atomicAdd(&gsum[i0], g0);  atomicAdd(&gsum[i1], g1);
    }
}

// ---------------- Offsets (prefix sum over 16) + aux loss ----------------
__global__ void offsets_aux_kernel(const int* __restrict__ counts,
                                   const float* __restrict__ gsum,
                                   int* __restrict__ offsets,
                                   float* __restrict__ aux_out) {
    if (threadIdx.x == 0) {
        int acc = 0;
        for (int e = 0; e < NEXP; e++) { offsets[e] = acc; acc += counts[e]; }
        offsets[NEXP] = acc;
        float tot = (float)acc;
        float s = 0.f;
        for (int e = 0; e < NEXP; e++) {
            float c = (float)counts[e];
            float f = c / tot;
            float m = gsum[e] / fmaxf(c, 1.f);
            s += f * m;
        }
        *aux_out = 0.02f * (s / (float)NEXP);
    }
}

// ---------------- Scatter assignments into expert-ordered list ----------------
__global__ void scatter_kernel(const int* __restrict__ idx,
                               const int* __restrict__ offsets,
                               int* __restrict__ poscnt, int* __restrict__ tlist) {
    int t = blockIdx.x * blockDim.x + threadIdx.x;
    if (t >= NASSIGN) return;
    int e = idx[t];
    int p = atomicAdd(&poscnt[e], 1);
    tlist[offsets[e] + p] = t;   // t = n*2 + k
}

__device__ __forceinline__ float gelu_tanh(float v) {
    float v3 = v * v * v;
    float t = tanhf(0.7978845608028654f * (v + 0.044715f * v3));
    return 0.5f * v * (1.f + t);
}

// ---------------- GEMM1: gathered X[ne,D] @ W1[e]^T -> gelu -> h_buf ----------------
__global__ __launch_bounds__(256)
void gemm1_kernel(const float* __restrict__ x, const float* __restrict__ w1,
                  const float* __restrict__ b1,
                  const int* __restrict__ offsets, const int* __restrict__ tlist,
                  float* __restrict__ h_buf) {
    int e = blockIdx.z;
    int beg = offsets[e], ne = offsets[e + 1] - beg;
    int row0 = blockIdx.x * BM;
    if (row0 >= ne) return;
    int col0 = blockIdx.y * BN;

    __shared__ float As[BK][BM + 4];
    __shared__ float Bs[BK][BN + 4];

    int tid = threadIdx.x;
    int lr = tid >> 4, lc = tid & 15;       // staging coords
    int tx = tid & 15, ty = tid >> 4;       // compute coords (16x16)

    int trow[4];
    #pragma unroll
    for (int i = 0; i < 4; i++) {
        int r = lr + i * 16;
        trow[i] = (row0 + r < ne) ? (tlist[beg + row0 + r] >> 1) : -1;
    }
    const float* w1e = w1 + ((size_t)e * HID + col0) * DIM;

    float acc[4][4] = {};
    for (int k0 = 0; k0 < DIM; k0 += BK) {
        #pragma unroll
        for (int i = 0; i < 4; i++) {
            int r = lr + i * 16;
            float v = 0.f;
            if (trow[i] >= 0) v = x[(size_t)trow[i] * DIM + k0 + lc];
            As[lc][r] = v;
            int nn = lr + i * 16;
            Bs[lc][nn] = w1e[(size_t)nn * DIM + k0 + lc];
        }
        __syncthreads();
        #pragma unroll
        for (int kk = 0; kk < BK; kk++) {
            float4 ra = *(const float4*)&As[kk][ty * 4];
            float4 rb = *(const float4*)&Bs[kk][tx * 4];
            float av[4] = {ra.x, ra.y, ra.z, ra.w};
            float bv[4] = {rb.x, rb.y, rb.z, rb.w};
            #pragma unroll
            for (int i = 0; i < 4; i++)
                #pragma unroll
                for (int j = 0; j < 4; j++)
                    acc[i][j] = fmaf(av[i], bv[j], acc[i][j]);
        }
        __syncthreads();
    }
    #pragma unroll
    for (int i = 0; i < 4; i++) {
        int r = ty * 4 + i;
        if (row0 + r >= ne) continue;
        size_t rowidx = (size_t)(beg + row0 + r);
        #pragma unroll
        for (int j = 0; j < 4; j++) {
            int c = col0 + tx * 4 + j;
            float v = acc[i][j] + b1[e * HID + c];
            h_buf[rowidx * HID + c] = gelu_tanh(v);
        }
    }
}

// ---------------- GEMM2: h[ne,H] @ W2[e]^T + b2, gate-scaled -> y_buf[t] ----------------
__global__ __launch_bounds__(256)
void gemm2_kernel(const float* __restrict__ h_buf, const float* __restrict__ w2,
                  const float* __restrict__ b2,
                  const int* __restrict__ offsets, const int* __restrict__ tlist,
                  const float* __restrict__ gate, float* __restrict__ y_buf) {
    int e = blockIdx.z;
    int beg = offsets[e], ne = offsets[e + 1] - beg;
    int row0 = blockIdx.x * BM;
    if (row0 >= ne) return;
    int col0 = blockIdx.y * BN;

    __shared__ float As[BK][BM + 4];
    __shared__ float Bs[BK][BN + 4];

    int tid = threadIdx.x;
    int lr = tid >> 4, lc = tid & 15;
    int tx = tid & 15, ty = tid >> 4;

    const float* w2e = w2 + ((size_t)e * DIM + col0) * HID;

    float acc[4][4] = {};
    for (int k0 = 0; k0 < HID; k0 += BK) {
        #pragma unroll
        for (int i = 0; i < 4; i++) {
            int r = lr + i * 16;
            As[lc][r] = (row0 + r < ne) ? h_buf[(size_t)(beg + row0 + r) * HID + k0 + lc] : 0.f;
            int nn = lr + i * 16;
            Bs[lc][nn] = w2e[(size_t)nn * HID + k0 + lc];
        }
        __syncthreads();
        #pragma unroll
        for (int kk = 0; kk < BK; kk++) {
            float4 ra = *(const float4*)&As[kk][ty * 4];
            float4 rb = *(const float4*)&Bs[kk][tx * 4];
            float av[4] = {ra.x, ra.y, ra.z, ra.w};
            float bv[4] = {rb.x, rb.y, rb.z, rb.w};
            #pragma unroll
            for (int i = 0; i < 4; i++)
                #pragma unroll
                for (int j = 0; j < 4; j++)
                    acc[i][j] = fmaf(av[i], bv[j], acc[i][j]);
        }
        __syncthreads();
    }
    #pragma unroll
    for (int i = 0; i < 4; i++) {
        int r = ty * 4 + i;
        if (row0 + r >= ne) continue;
        int t = tlist[beg + row0 + r];
        float g = gate[t];
        #pragma unroll
        for (int j = 0; j < 4; j++) {
            int c = col0 + tx * 4 + j;
            float v = g * (acc[i][j] + b2[e * DIM + c]);
            y_buf[(size_t)t * DIM + c] = v;
        }
    }
}

// ---------------- Combine the two expert slots per token -> fp32 out ----------------
__global__ void combine_kernel(const float* __restrict__ y_buf,
                               float* __restrict__ out) {
    int i = blockIdx.x * blockDim.x + threadIdx.x;  // over N*D/4
    int n = i >> 8;            // DIM/4 = 256 float4 per token
    int dv = i & 255;
    const float4* yb = (const float4*)y_buf;
    float4 a = yb[(size_t)(2 * n) * 256 + dv];
    float4 b = yb[(size_t)(2 * n + 1) * 256 + dv];
    float4 o;
    o.x = a.x + b.x;
    o.y = a.y + b.y;
    o.z = a.z + b.z;
    o.w = a.w + b.w;
    ((float4*)out)[i] = o;
}

extern "C" void kernel_launch(void* const* d_in, const int* in_sizes, int n_in,
                              void* d_out, int out_size, void* d_ws, size_t ws_size,
                              hipStream_t stream) {
    const float* x  = (const float*)d_in[0];
    const float* rw = (const float*)d_in[1];
    const float* w1 = (const float*)d_in[2];
    const float* b1 = (const float*)d_in[3];
    const float* w2 = (const float*)d_in[4];
    const float* b2 = (const float*)d_in[5];
    float* out = (float*)d_out;   // fp32 output: reference computes in float32

    // Workspace layout (floats/ints)
    int*   counts  = (int*)d_ws;                         // 16
    float* gsum    = (float*)d_ws + 16;                  // 16
    int*   poscnt  = (int*)d_ws + 32;                    // 16
    int*   offsets = (int*)d_ws + 48;                    // 17
    int*   idx     = (int*)d_ws + 72;                    // 8192
    float* gate    = (float*)d_ws + 72 + NASSIGN;        // 8192
    int*   tlist   = (int*)d_ws + 72 + 2 * NASSIGN;      // 8192
    float* h_buf   = (float*)d_ws + 32768;               // 8192*1536
    float* y_buf   = h_buf + (size_t)NASSIGN * HID;      // 8192*1024

    hipMemsetAsync(d_ws, 0, 192, stream);  // counts+gsum+poscnt

    router_kernel<<<N_TOK, 256, 0, stream>>>(x, rw, counts, gsum, idx, gate);
    offsets_aux_kernel<<<1, 64, 0, stream>>>(counts, gsum, offsets,
                                             out + (size_t)N_TOK * DIM);
    scatter_kernel<<<NASSIGN / 256, 256, 0, stream>>>(idx, offsets, poscnt, tlist);
    gemm1_kernel<<<dim3(64, HID / BN, NEXP), 256, 0, stream>>>(x, w1, b1, offsets, tlist, h_buf);
    gemm2_kernel<<<dim3(64, DIM / BN, NEXP), 256, 0, stream>>>(h_buf, w2, b2, offsets, tlist, gate, y_buf);
    combine_kernel<<<(N_TOK * DIM / 4) / 256, 256, 0, stream>>>(y_buf, out);
}

// Round 3
// 1195.617 us; speedup vs baseline: 2.1644x; 2.1644x over previous
//
#include <hip/hip_runtime.h>
#include <hip/hip_bf16.h>
#include <math.h>

// Problem constants (fixed by the reference)
#define N_TOK 4096
#define DIM   1024
#define NEXP  16
#define HID   1536
#define TOPK2 2
#define NASSIGN (N_TOK * TOPK2)   // 8192

typedef __attribute__((ext_vector_type(8))) short short8;   // bf16x8 MFMA A/B frag
typedef __attribute__((ext_vector_type(4))) float floatx4;  // fp32x4 MFMA C/D frag
typedef unsigned short u16;

// async global->LDS, 16B per lane; LDS dest = wave-uniform base + lane*16
#define GLOAD_LDS16(gp, lp)                                                     \
    __builtin_amdgcn_global_load_lds(                                           \
        (const __attribute__((address_space(1))) unsigned int*)(gp),            \
        (__attribute__((address_space(3))) unsigned int*)(lp), 16, 0, 0)

// ---------------- fp32 -> bf16 conversion (vectorized) ----------------
__global__ void cvt_kernel(const float* __restrict__ src, u16* __restrict__ dst, int n4) {
    int i = blockIdx.x * 256 + threadIdx.x;
    if (i >= n4) return;
    float4 v = ((const float4*)src)[i];
    __hip_bfloat16 a = __float2bfloat16(v.x), b = __float2bfloat16(v.y);
    __hip_bfloat16 c = __float2bfloat16(v.z), d = __float2bfloat16(v.w);
    ushort4 o;
    o.x = *(u16*)&a; o.y = *(u16*)&b; o.z = *(u16*)&c; o.w = *(u16*)&d;
    ((ushort4*)dst)[i] = o;
}

// ---------------- Router: one block per token (fp32, exact top-k) ----------------
__global__ void router_kernel(const float* __restrict__ x,
                              const float* __restrict__ rw,
                              int* __restrict__ counts, float* __restrict__ gsum,
                              int* __restrict__ idx, float* __restrict__ gate) {
    int n = blockIdx.x;
    __shared__ float xs[DIM];
    __shared__ float lg[NEXP];
    const float* xr = x + (size_t)n * DIM;
    for (int d = threadIdx.x; d < DIM; d += 256) xs[d] = xr[d];
    __syncthreads();
    int wave = threadIdx.x >> 6, lane = threadIdx.x & 63;
    for (int e = wave; e < NEXP; e += 4) {
        const float* wr = rw + (size_t)e * DIM;
        float s = 0.f;
        for (int d = lane; d < DIM; d += 64) s += xs[d] * wr[d];
        #pragma unroll
        for (int off = 32; off > 0; off >>= 1) s += __shfl_down(s, off, 64);
        if (lane == 0) lg[e] = s;
    }
    __syncthreads();
    if (threadIdx.x == 0) {
        float v0 = -3.402823466e+38f, v1 = -3.402823466e+38f;
        int i0 = 0, i1 = 0;
        for (int e = 0; e < NEXP; e++) {
            float v = lg[e];
            if (v > v0) { v1 = v0; i1 = i0; v0 = v; i0 = e; }
            else if (v > v1) { v1 = v; i1 = e; }
        }
        float e1 = expf(v1 - v0);
        float inv = 1.f / (1.f + e1);
        float g0 = inv, g1 = e1 * inv;
        idx[2 * n] = i0; idx[2 * n + 1] = i1;
        gate[2 * n] = g0; gate[2 * n + 1] = g1;
        atomicAdd(&counts[i0], 1); atomicAdd(&counts[i1], 1);
        atomicAdd(&gsum[i0], g0);  atomicAdd(&gsum[i1], g1);
    }
}

// ---------------- Offsets (prefix sum over 16) + aux loss ----------------
__global__ void offsets_aux_kernel(const int* __restrict__ counts,
                                   const float* __restrict__ gsum,
                                   int* __restrict__ offsets,
                                   float* __restrict__ aux_out) {
    if (threadIdx.x == 0) {
        int acc = 0;
        for (int e = 0; e < NEXP; e++) { offsets[e] = acc; acc += counts[e]; }
        offsets[NEXP] = acc;
        float tot = (float)acc;
        float s = 0.f;
        for (int e = 0; e < NEXP; e++) {
            float c = (float)counts[e];
            float f = c / tot;
            float m = gsum[e] / fmaxf(c, 1.f);
            s += f * m;
        }
        *aux_out = 0.02f * (s / (float)NEXP);
    }
}

// ---------------- Scatter assignments into expert-ordered list ----------------
__global__ void scatter_kernel(const int* __restrict__ idx,
                               const int* __restrict__ offsets,
                               int* __restrict__ poscnt, int* __restrict__ tlist) {
    int t = blockIdx.x * blockDim.x + threadIdx.x;
    if (t >= NASSIGN) return;
    int e = idx[t];
    int p = atomicAdd(&poscnt[e], 1);
    tlist[offsets[e] + p] = t;   // t = n*2 + k
}

__device__ __forceinline__ float gelu_tanh(float v) {
    float v3 = v * v * v;
    float t = tanhf(0.7978845608028654f * (v + 0.044715f * v3));
    return 0.5f * v * (1.f + t);
}

// =====================================================================
// MFMA grouped GEMM, 128x128 tile, BK=32 bf16, 4 waves (each 64x64).
// A rows gathered via tlist (gemm1: token rows of x_bf; gemm2: h_bf rows).
// B = weight rows (output-channel-major, contiguous K) -> C = A*W^T.
// =====================================================================

// GEMM1: h[a, :] = gelu(x[tok(a)] @ w1[e]^T + b1[e]),  K=DIM=1024, N=HID=1536
__global__ __launch_bounds__(256)
void gemm1_kernel(const u16* __restrict__ xb, const u16* __restrict__ w1b,
                  const float* __restrict__ b1,
                  const int* __restrict__ offsets, const int* __restrict__ tlist,
                  u16* __restrict__ h_bf) {
    int e = blockIdx.z;
    int beg = offsets[e], ne = offsets[e + 1] - beg;
    int row0 = blockIdx.x * 128;
    if (row0 >= ne) return;
    int col0 = blockIdx.y * 128;

    __shared__ u16 As[128 * 32];
    __shared__ u16 Bs[128 * 32];

    int tid = threadIdx.x;
    int wave = tid >> 6, lane = tid & 63;
    int wm = wave & 1, wn = wave >> 1;

    // Staging geometry: wave stages rows [wave*32, wave*32+32) in 2 insts of 16 rows.
    // lane covers row (lane>>2), k-chunk (lane&3)*8.
    int koff = (lane & 3) * 8;
    const u16* aptr[2];
    const u16* bptr[2];
    #pragma unroll
    for (int q = 0; q < 2; q++) {
        int lrow = wave * 32 + q * 16 + (lane >> 2);
        int gi = beg + row0 + lrow;
        int gi2 = (row0 + lrow < ne) ? gi : beg;     // clamp OOB rows to a valid row
        int tok = tlist[gi2] >> 1;
        aptr[q] = xb + (size_t)tok * DIM + koff;
        int n = col0 + lrow;                          // B row = output col, always < HID
        bptr[q] = w1b + (size_t)(e * HID + n) * DIM + koff;
    }

    floatx4 acc[4][4] = {};
    for (int k0 = 0; k0 < DIM; k0 += 32) {
        #pragma unroll
        for (int q = 0; q < 2; q++) {
            GLOAD_LDS16(aptr[q] + k0, &As[(wave * 32 + q * 16) * 32]);
            GLOAD_LDS16(bptr[q] + k0, &Bs[(wave * 32 + q * 16) * 32]);
        }
        __syncthreads();
        short8 af[4], bf_[4];
        #pragma unroll
        for (int mi = 0; mi < 4; mi++)
            af[mi] = *(const short8*)&As[(wm * 64 + mi * 16 + (lane & 15)) * 32 + (lane >> 4) * 8];
        #pragma unroll
        for (int nj = 0; nj < 4; nj++)
            bf_[nj] = *(const short8*)&Bs[(wn * 64 + nj * 16 + (lane & 15)) * 32 + (lane >> 4) * 8];
        #pragma unroll
        for (int mi = 0; mi < 4; mi++)
            #pragma unroll
            for (int nj = 0; nj < 4; nj++)
                acc[mi][nj] = __builtin_amdgcn_mfma_f32_16x16x32_bf16(af[mi], bf_[nj], acc[mi][nj], 0, 0, 0);
        __syncthreads();
    }

    // Epilogue: C/D layout col=lane&15, row=(lane>>4)*4+reg
    #pragma unroll
    for (int mi = 0; mi < 4; mi++) {
        #pragma unroll
        for (int r = 0; r < 4; r++) {
            int lrow = wm * 64 + mi * 16 + (lane >> 4) * 4 + r;
            if (row0 + lrow >= ne) continue;
            size_t orow = (size_t)(beg + row0 + lrow);
            #pragma unroll
            for (int nj = 0; nj < 4; nj++) {
                int col = col0 + wn * 64 + nj * 16 + (lane & 15);
                float v = acc[mi][nj][r] + b1[e * HID + col];
                __hip_bfloat16 hb = __float2bfloat16(gelu_tanh(v));
                h_bf[orow * HID + col] = *(u16*)&hb;
            }
        }
    }
}

// GEMM2: out[tok(a)] += gate(a) * (h[a] @ w2[e]^T + b2[e]),  K=HID=1536, N=DIM=1024
__global__ __launch_bounds__(256)
void gemm2_kernel(const u16* __restrict__ h_bf, const u16* __restrict__ w2b,
                  const float* __restrict__ b2,
                  const int* __restrict__ offsets, const int* __restrict__ tlist,
                  const float* __restrict__ gate, float* __restrict__ out) {
    int e = blockIdx.z;
    int beg = offsets[e], ne = offsets[e + 1] - beg;
    int row0 = blockIdx.x * 128;
    if (row0 >= ne) return;
    int col0 = blockIdx.y * 128;

    __shared__ u16 As[128 * 32];
    __shared__ u16 Bs[128 * 32];

    int tid = threadIdx.x;
    int wave = tid >> 6, lane = tid & 63;
    int wm = wave & 1, wn = wave >> 1;

    int koff = (lane & 3) * 8;
    const u16* aptr[2];
    const u16* bptr[2];
    #pragma unroll
    for (int q = 0; q < 2; q++) {
        int lrow = wave * 32 + q * 16 + (lane >> 2);
        int gi = beg + row0 + lrow;
        int gi2 = (row0 + lrow < ne) ? gi : beg;
        aptr[q] = h_bf + (size_t)gi2 * HID + koff;
        int n = col0 + lrow;                          // < DIM always
        bptr[q] = w2b + (size_t)(e * DIM + n) * HID + koff;
    }

    floatx4 acc[4][4] = {};
    for (int k0 = 0; k0 < HID; k0 += 32) {
        #pragma unroll
        for (int q = 0; q < 2; q++) {
            GLOAD_LDS16(aptr[q] + k0, &As[(wave * 32 + q * 16) * 32]);
            GLOAD_LDS16(bptr[q] + k0, &Bs[(wave * 32 + q * 16) * 32]);
        }
        __syncthreads();
        short8 af[4], bf_[4];
        #pragma unroll
        for (int mi = 0; mi < 4; mi++)
            af[mi] = *(const short8*)&As[(wm * 64 + mi * 16 + (lane & 15)) * 32 + (lane >> 4) * 8];
        #pragma unroll
        for (int nj = 0; nj < 4; nj++)
            bf_[nj] = *(const short8*)&Bs[(wn * 64 + nj * 16 + (lane & 15)) * 32 + (lane >> 4) * 8];
        #pragma unroll
        for (int mi = 0; mi < 4; mi++)
            #pragma unroll
            for (int nj = 0; nj < 4; nj++)
                acc[mi][nj] = __builtin_amdgcn_mfma_f32_16x16x32_bf16(af[mi], bf_[nj], acc[mi][nj], 0, 0, 0);
        __syncthreads();
    }

    #pragma unroll
    for (int mi = 0; mi < 4; mi++) {
        #pragma unroll
        for (int r = 0; r < 4; r++) {
            int lrow = wm * 64 + mi * 16 + (lane >> 4) * 4 + r;
            if (row0 + lrow >= ne) continue;
            int t = tlist[beg + row0 + lrow];
            float g = gate[t];
            int tok = t >> 1;
            #pragma unroll
            for (int nj = 0; nj < 4; nj++) {
                int col = col0 + wn * 64 + nj * 16 + (lane & 15);
                float v = g * (acc[mi][nj][r] + b2[e * DIM + col]);
                atomicAdd(&out[(size_t)tok * DIM + col], v);
            }
        }
    }
}

extern "C" void kernel_launch(void* const* d_in, const int* in_sizes, int n_in,
                              void* d_out, int out_size, void* d_ws, size_t ws_size,
                              hipStream_t stream) {
    const float* x  = (const float*)d_in[0];
    const float* rw = (const float*)d_in[1];
    const float* w1 = (const float*)d_in[2];
    const float* b1 = (const float*)d_in[3];
    const float* w2 = (const float*)d_in[4];
    const float* b2 = (const float*)d_in[5];
    float* out = (float*)d_out;   // fp32 output [N*D main | 1 aux]

    // ---- workspace layout (bytes) ----
    char* ws = (char*)d_ws;
    int*   counts  = (int*)(ws + 0);          // 16
    float* gsum    = (float*)(ws + 64);       // 16
    int*   poscnt  = (int*)(ws + 128);        // 16
    int*   offsets = (int*)(ws + 192);        // 17
    int*   idx     = (int*)(ws + 320);        // 8192
    float* gate    = (float*)(ws + 320 + 4 * NASSIGN);
    int*   tlist   = (int*)(ws + 320 + 8 * NASSIGN);
    u16*   x_bf    = (u16*)(ws + (128 << 10));                        // 8 MB
    u16*   h_bf    = x_bf + (size_t)N_TOK * DIM;                      // 25.2 MB
    u16*   w_bf    = h_bf + (size_t)NASSIGN * HID;                    // 50.3 MB (w1 then w2)
    // total ~= 83.8 MB (round-2 proved >= 84 MB available)

    hipMemsetAsync(d_ws, 0, 192, stream);                 // counts+gsum+poscnt
    hipMemsetAsync(d_out, 0, (size_t)out_size * 4, stream); // zero for atomic combine

    cvt_kernel<<<(N_TOK * DIM / 4 + 255) / 256, 256, 0, stream>>>(x, x_bf, N_TOK * DIM / 4);
    cvt_kernel<<<(NEXP * HID * DIM / 4 + 255) / 256, 256, 0, stream>>>(w1, w_bf, NEXP * HID * DIM / 4);

    router_kernel<<<N_TOK, 256, 0, stream>>>(x, rw, counts, gsum, idx, gate);
    offsets_aux_kernel<<<1, 64, 0, stream>>>(counts, gsum, offsets, out + (size_t)N_TOK * DIM);
    scatter_kernel<<<NASSIGN / 256, 256, 0, stream>>>(idx, offsets, poscnt, tlist);

    gemm1_kernel<<<dim3(NASSIGN / 128, HID / 128, NEXP), 256, 0, stream>>>(
        x_bf, w_bf, b1, offsets, tlist, h_bf);

    cvt_kernel<<<(NEXP * DIM * HID / 4 + 255) / 256, 256, 0, stream>>>(w2, w_bf, NEXP * DIM * HID / 4);

    gemm2_kernel<<<dim3(NASSIGN / 128, DIM / 128, NEXP), 256, 0, stream>>>(
        h_bf, w_bf, b2, offsets, tlist, gate, out);
}

// Round 4
// 588.443 us; speedup vs baseline: 4.3976x; 2.0318x over previous
//
#include <hip/hip_runtime.h>
#include <hip/hip_bf16.h>
#include <math.h>

// Problem constants (fixed by the reference)
#define N_TOK 4096
#define DIM   1024
#define NEXP  16
#define HID   1536
#define TOPK2 2
#define NASSIGN (N_TOK * TOPK2)   // 8192

#define MAX_ITEMS 80   // worst-case sum_e ceil(ne/128) = 79

typedef __attribute__((ext_vector_type(8))) short short8;   // bf16x8 MFMA A/B frag
typedef __attribute__((ext_vector_type(4))) float floatx4;  // fp32x4 MFMA C/D frag
typedef unsigned short u16;

// async global->LDS, 16B per lane; LDS dest = wave-uniform base + lane*16
#define GLOAD_LDS16(gp, lp)                                                     \
    __builtin_amdgcn_global_load_lds(                                           \
        (const __attribute__((address_space(1))) unsigned int*)(gp),            \
        (__attribute__((address_space(3))) unsigned int*)(lp), 16, 0, 0)

// ---------------- fp32 -> bf16 conversion (vectorized) ----------------
__global__ void cvt_kernel(const float* __restrict__ src, u16* __restrict__ dst, int n4) {
    int i = blockIdx.x * 256 + threadIdx.x;
    if (i >= n4) return;
    float4 v = ((const float4*)src)[i];
    __hip_bfloat16 a = __float2bfloat16(v.x), b = __float2bfloat16(v.y);
    __hip_bfloat16 c = __float2bfloat16(v.z), d = __float2bfloat16(v.w);
    ushort4 o;
    o.x = *(u16*)&a; o.y = *(u16*)&b; o.z = *(u16*)&c; o.w = *(u16*)&d;
    ((ushort4*)dst)[i] = o;
}

// ---------------- Router: one block per token (fp32, exact top-k) ----------------
__global__ void router_kernel(const float* __restrict__ x,
                              const float* __restrict__ rw,
                              int* __restrict__ counts, float* __restrict__ gsum,
                              int* __restrict__ idx, float* __restrict__ gate) {
    int n = blockIdx.x;
    __shared__ float xs[DIM];
    __shared__ float lg[NEXP];
    const float* xr = x + (size_t)n * DIM;
    for (int d = threadIdx.x; d < DIM; d += 256) xs[d] = xr[d];
    __syncthreads();
    int wave = threadIdx.x >> 6, lane = threadIdx.x & 63;
    for (int e = wave; e < NEXP; e += 4) {
        const float* wr = rw + (size_t)e * DIM;
        float s = 0.f;
        for (int d = lane; d < DIM; d += 64) s += xs[d] * wr[d];
        #pragma unroll
        for (int off = 32; off > 0; off >>= 1) s += __shfl_down(s, off, 64);
        if (lane == 0) lg[e] = s;
    }
    __syncthreads();
    if (threadIdx.x == 0) {
        float v0 = -3.402823466e+38f, v1 = -3.402823466e+38f;
        int i0 = 0, i1 = 0;
        for (int e = 0; e < NEXP; e++) {
            float v = lg[e];
            if (v > v0) { v1 = v0; i1 = i0; v0 = v; i0 = e; }
            else if (v > v1) { v1 = v; i1 = e; }
        }
        float e1 = expf(v1 - v0);
        float inv = 1.f / (1.f + e1);
        float g0 = inv, g1 = e1 * inv;
        idx[2 * n] = i0; idx[2 * n + 1] = i1;
        gate[2 * n] = g0; gate[2 * n + 1] = g1;
        atomicAdd(&counts[i0], 1); atomicAdd(&counts[i1], 1);
        atomicAdd(&gsum[i0], g0);  atomicAdd(&gsum[i1], g1);
    }
}

// ------- Offsets + aux loss + compacted (expert,row-tile) worklist -------
__global__ void offsets_aux_kernel(const int* __restrict__ counts,
                                   const float* __restrict__ gsum,
                                   int* __restrict__ offsets,
                                   int* __restrict__ wl, int* __restrict__ wcount,
                                   float* __restrict__ aux_out) {
    if (threadIdx.x == 0) {
        int acc = 0;
        for (int e = 0; e < NEXP; e++) { offsets[e] = acc; acc += counts[e]; }
        offsets[NEXP] = acc;
        float tot = (float)acc;
        float s = 0.f;
        for (int e = 0; e < NEXP; e++) {
            float c = (float)counts[e];
            float f = c / tot;
            float m = gsum[e] / fmaxf(c, 1.f);
            s += f * m;
        }
        *aux_out = 0.02f * (s / (float)NEXP);
        int m = 0;
        for (int e = 0; e < NEXP; e++) {
            int nt = (counts[e] + 127) >> 7;
            for (int rt = 0; rt < nt; rt++) wl[m++] = (e << 8) | rt;
        }
        *wcount = m;
    }
}

// ---------------- Scatter assignments into expert-ordered list ----------------
__global__ void scatter_kernel(const int* __restrict__ idx,
                               const int* __restrict__ offsets,
                               int* __restrict__ poscnt, int* __restrict__ tlist) {
    int t = blockIdx.x * blockDim.x + threadIdx.x;
    if (t >= NASSIGN) return;
    int e = idx[t];
    int p = atomicAdd(&poscnt[e], 1);
    tlist[offsets[e] + p] = t;   // t = n*2 + k
}

__device__ __forceinline__ float gelu_tanh(float v) {
    float v3 = v * v * v;
    float t = tanhf(0.7978845608028654f * (v + 0.044715f * v3));
    return 0.5f * v * (1.f + t);
}

// =====================================================================
// MFMA grouped GEMM, 128x128 tile, BK=32 bf16, 4 waves (each 64x64).
// Dense worklist grid: bid -> (worklist item, col-tile). XOR-swizzled LDS:
// LDS 16B-chunk c of row r holds global chunk c ^ ((r>>1)&3)  -> 2-way
// bank access (free) instead of 8-way on fragment ds_read_b128.
// =====================================================================

// GEMM1: h[a, :] = gelu(x[tok(a)] @ w1[e]^T + b1[e]),  K=DIM=1024, N=HID=1536
__global__ __launch_bounds__(256)
void gemm1_kernel(const u16* __restrict__ xb, const u16* __restrict__ w1b,
                  const float* __restrict__ b1,
                  const int* __restrict__ offsets, const int* __restrict__ tlist,
                  const int* __restrict__ wl, const int* __restrict__ wcount,
                  u16* __restrict__ h_bf) {
    int bid = blockIdx.x;
    int item = bid / 12;
    if (item >= *wcount) return;
    int colt = bid - item * 12;
    int w = wl[item];
    int e = w >> 8, rt = w & 255;
    int beg = offsets[e], ne = offsets[e + 1] - beg;
    int row0 = rt * 128, col0 = colt * 128;

    __shared__ u16 As[128 * 32];
    __shared__ u16 Bs[128 * 32];

    int tid = threadIdx.x;
    int wave = tid >> 6, lane = tid & 63;
    int wm = wave & 1, wn = wave >> 1;

    // Staging: lane covers row (lane>>2), global k-chunk ((lane&3) ^ g) where
    // g = (row>>1)&3 = (lane>>3)&3 (wave/q offsets are multiples of 4 rows).
    int koff = (((lane & 3) ^ ((lane >> 3) & 3)) * 8);
    const u16* aptr[2];
    const u16* bptr[2];
    #pragma unroll
    for (int q = 0; q < 2; q++) {
        int lrow = wave * 32 + q * 16 + (lane >> 2);
        int gi = beg + row0 + lrow;
        int gi2 = (row0 + lrow < ne) ? gi : beg;     // clamp OOB rows to a valid row
        int tok = tlist[gi2] >> 1;
        aptr[q] = xb + (size_t)tok * DIM + koff;
        int n = col0 + lrow;                          // B row = output col, always < HID
        bptr[q] = w1b + (size_t)(e * HID + n) * DIM + koff;
    }

    // Fragment read chunk: want global chunk (lane>>4); stored at LDS chunk
    // (lane>>4) ^ g with g = ((lane&15)>>1)&3 = (lane>>1)&3.
    int rchunk = (((lane >> 4) ^ ((lane >> 1) & 3)) * 8);

    floatx4 acc[4][4] = {};
    for (int k0 = 0; k0 < DIM; k0 += 32) {
        #pragma unroll
        for (int q = 0; q < 2; q++) {
            GLOAD_LDS16(aptr[q] + k0, &As[(wave * 32 + q * 16) * 32]);
            GLOAD_LDS16(bptr[q] + k0, &Bs[(wave * 32 + q * 16) * 32]);
        }
        __syncthreads();
        short8 af[4], bf_[4];
        #pragma unroll
        for (int mi = 0; mi < 4; mi++)
            af[mi] = *(const short8*)&As[(wm * 64 + mi * 16 + (lane & 15)) * 32 + rchunk];
        #pragma unroll
        for (int nj = 0; nj < 4; nj++)
            bf_[nj] = *(const short8*)&Bs[(wn * 64 + nj * 16 + (lane & 15)) * 32 + rchunk];
        #pragma unroll
        for (int mi = 0; mi < 4; mi++)
            #pragma unroll
            for (int nj = 0; nj < 4; nj++)
                acc[mi][nj] = __builtin_amdgcn_mfma_f32_16x16x32_bf16(af[mi], bf_[nj], acc[mi][nj], 0, 0, 0);
        __syncthreads();
    }

    // Epilogue: C/D layout col=lane&15, row=(lane>>4)*4+reg
    #pragma unroll
    for (int mi = 0; mi < 4; mi++) {
        #pragma unroll
        for (int r = 0; r < 4; r++) {
            int lrow = wm * 64 + mi * 16 + (lane >> 4) * 4 + r;
            if (row0 + lrow >= ne) continue;
            size_t orow = (size_t)(beg + row0 + lrow);
            #pragma unroll
            for (int nj = 0; nj < 4; nj++) {
                int col = col0 + wn * 64 + nj * 16 + (lane & 15);
                float v = acc[mi][nj][r] + b1[e * HID + col];
                __hip_bfloat16 hb = __float2bfloat16(gelu_tanh(v));
                h_bf[orow * HID + col] = *(u16*)&hb;
            }
        }
    }
}

// GEMM2: out[tok(a)] += gate(a) * (h[a] @ w2[e]^T + b2[e]),  K=HID=1536, N=DIM=1024
__global__ __launch_bounds__(256)
void gemm2_kernel(const u16* __restrict__ h_bf, const u16* __restrict__ w2b,
                  const float* __restrict__ b2,
                  const int* __restrict__ offsets, const int* __restrict__ tlist,
                  const int* __restrict__ wl, const int* __restrict__ wcount,
                  const float* __restrict__ gate, float* __restrict__ out) {
    int bid = blockIdx.x;
    int item = bid >> 3;
    if (item >= *wcount) return;
    int colt = bid & 7;
    int w = wl[item];
    int e = w >> 8, rt = w & 255;
    int beg = offsets[e], ne = offsets[e + 1] - beg;
    int row0 = rt * 128, col0 = colt * 128;

    __shared__ u16 As[128 * 32];
    __shared__ u16 Bs[128 * 32];

    int tid = threadIdx.x;
    int wave = tid >> 6, lane = tid & 63;
    int wm = wave & 1, wn = wave >> 1;

    int koff = (((lane & 3) ^ ((lane >> 3) & 3)) * 8);
    const u16* aptr[2];
    const u16* bptr[2];
    #pragma unroll
    for (int q = 0; q < 2; q++) {
        int lrow = wave * 32 + q * 16 + (lane >> 2);
        int gi = beg + row0 + lrow;
        int gi2 = (row0 + lrow < ne) ? gi : beg;
        aptr[q] = h_bf + (size_t)gi2 * HID + koff;
        int n = col0 + lrow;                          // < DIM always
        bptr[q] = w2b + (size_t)(e * DIM + n) * HID + koff;
    }

    int rchunk = (((lane >> 4) ^ ((lane >> 1) & 3)) * 8);

    floatx4 acc[4][4] = {};
    for (int k0 = 0; k0 < HID; k0 += 32) {
        #pragma unroll
        for (int q = 0; q < 2; q++) {
            GLOAD_LDS16(aptr[q] + k0, &As[(wave * 32 + q * 16) * 32]);
            GLOAD_LDS16(bptr[q] + k0, &Bs[(wave * 32 + q * 16) * 32]);
        }
        __syncthreads();
        short8 af[4], bf_[4];
        #pragma unroll
        for (int mi = 0; mi < 4; mi++)
            af[mi] = *(const short8*)&As[(wm * 64 + mi * 16 + (lane & 15)) * 32 + rchunk];
        #pragma unroll
        for (int nj = 0; nj < 4; nj++)
            bf_[nj] = *(const short8*)&Bs[(wn * 64 + nj * 16 + (lane & 15)) * 32 + rchunk];
        #pragma unroll
        for (int mi = 0; mi < 4; mi++)
            #pragma unroll
            for (int nj = 0; nj < 4; nj++)
                acc[mi][nj] = __builtin_amdgcn_mfma_f32_16x16x32_bf16(af[mi], bf_[nj], acc[mi][nj], 0, 0, 0);
        __syncthreads();
    }

    #pragma unroll
    for (int mi = 0; mi < 4; mi++) {
        #pragma unroll
        for (int r = 0; r < 4; r++) {
            int lrow = wm * 64 + mi * 16 + (lane >> 4) * 4 + r;
            if (row0 + lrow >= ne) continue;
            int t = tlist[beg + row0 + lrow];
            float g = gate[t];
            int tok = t >> 1;
            #pragma unroll
            for (int nj = 0; nj < 4; nj++) {
                int col = col0 + wn * 64 + nj * 16 + (lane & 15);
                float v = g * (acc[mi][nj][r] + b2[e * DIM + col]);
                atomicAdd(&out[(size_t)tok * DIM + col], v);
            }
        }
    }
}

extern "C" void kernel_launch(void* const* d_in, const int* in_sizes, int n_in,
                              void* d_out, int out_size, void* d_ws, size_t ws_size,
                              hipStream_t stream) {
    const float* x  = (const float*)d_in[0];
    const float* rw = (const float*)d_in[1];
    const float* w1 = (const float*)d_in[2];
    const float* b1 = (const float*)d_in[3];
    const float* w2 = (const float*)d_in[4];
    const float* b2 = (const float*)d_in[5];
    float* out = (float*)d_out;   // fp32 output [N*D main | 1 aux]

    // ---- workspace layout (bytes) ----
    char* ws = (char*)d_ws;
    int*   counts  = (int*)(ws + 0);          // 16
    float* gsum    = (float*)(ws + 64);       // 16
    int*   poscnt  = (int*)(ws + 128);        // 16
    int*   offsets = (int*)(ws + 192);        // 17
    int*   wcount  = (int*)(ws + 384);        // 1
    int*   wl      = (int*)(ws + 512);        // up to 128
    int*   idx     = (int*)(ws + 4096);                               // 32 KB
    float* gate    = (float*)(ws + 4096 + 4 * NASSIGN);               // 32 KB
    int*   tlist   = (int*)(ws + 4096 + 8 * NASSIGN);                 // 32 KB
    u16*   x_bf    = (u16*)(ws + (128 << 10));                        // 8 MB
    u16*   h_bf    = x_bf + (size_t)N_TOK * DIM;                      // 25.2 MB
    u16*   w_bf    = h_bf + (size_t)NASSIGN * HID;                    // 50.3 MB (w1 then w2)

    hipMemsetAsync(d_ws, 0, 192, stream);                   // counts+gsum+poscnt
    hipMemsetAsync(d_out, 0, (size_t)out_size * 4, stream); // zero for atomic combine

    cvt_kernel<<<(N_TOK * DIM / 4 + 255) / 256, 256, 0, stream>>>(x, x_bf, N_TOK * DIM / 4);
    cvt_kernel<<<(NEXP * HID * DIM / 4 + 255) / 256, 256, 0, stream>>>(w1, w_bf, NEXP * HID * DIM / 4);

    router_kernel<<<N_TOK, 256, 0, stream>>>(x, rw, counts, gsum, idx, gate);
    offsets_aux_kernel<<<1, 64, 0, stream>>>(counts, gsum, offsets, wl, wcount,
                                             out + (size_t)N_TOK * DIM);
    scatter_kernel<<<NASSIGN / 256, 256, 0, stream>>>(idx, offsets, poscnt, tlist);

    gemm1_kernel<<<MAX_ITEMS * 12, 256, 0, stream>>>(
        x_bf, w_bf, b1, offsets, tlist, wl, wcount, h_bf);

    cvt_kernel<<<(NEXP * DIM * HID / 4 + 255) / 256, 256, 0, stream>>>(w2, w_bf, NEXP * DIM * HID / 4);

    gemm2_kernel<<<MAX_ITEMS * 8, 256, 0, stream>>>(
        h_bf, w_bf, b2, offsets, tlist, wl, wcount, gate, out);
}

// Round 5
// 457.115 us; speedup vs baseline: 5.6611x; 1.2873x over previous
//
#include <hip/hip_runtime.h>
#include <hip/hip_bf16.h>
#include <math.h>

// Problem constants (fixed by the reference)
#define N_TOK 4096
#define DIM   1024
#define NEXP  16
#define HID   1536
#define TOPK2 2
#define NASSIGN (N_TOK * TOPK2)   // 8192

#define MAX_ITEMS 80   // worst-case sum_e ceil(ne/128) = 79

typedef __attribute__((ext_vector_type(8))) short short8;   // bf16x8 MFMA A/B frag
typedef __attribute__((ext_vector_type(4))) float floatx4;  // fp32x4 MFMA C/D frag
typedef unsigned short u16;

// async global->LDS, 16B per lane; LDS dest = wave-uniform base + lane*16
#define GLOAD_LDS16(gp, lp)                                                     \
    __builtin_amdgcn_global_load_lds(                                           \
        (const __attribute__((address_space(1))) unsigned int*)(gp),            \
        (__attribute__((address_space(3))) unsigned int*)(lp), 16, 0, 0)

// ---------------- fp32 -> bf16 conversion (vectorized) ----------------
__global__ void cvt_kernel(const float* __restrict__ src, u16* __restrict__ dst, int n4) {
    int i = blockIdx.x * 256 + threadIdx.x;
    if (i >= n4) return;
    float4 v = ((const float4*)src)[i];
    __hip_bfloat16 a = __float2bfloat16(v.x), b = __float2bfloat16(v.y);
    __hip_bfloat16 c = __float2bfloat16(v.z), d = __float2bfloat16(v.w);
    ushort4 o;
    o.x = *(u16*)&a; o.y = *(u16*)&b; o.z = *(u16*)&c; o.w = *(u16*)&d;
    ((ushort4*)dst)[i] = o;
}

// ---------- Router logits + top-2 + gates: tiled fp32 GEMM, no atomics ----------
// 256 blocks x 16 tokens. Thread (t,e) = (tid>>4, tid&15) accumulates one logit.
// LDS rows stride 68 floats: float4-store aligned (68%4==0), bank offset 4/row
// -> 2-way conflicts max (free, m136).
__global__ __launch_bounds__(256)
void logits_topk_kernel(const float* __restrict__ x, const float* __restrict__ rw,
                        int* __restrict__ idx, float* __restrict__ gate) {
    int tb = blockIdx.x * 16;
    __shared__ float xs[16][68];
    __shared__ float rs[16][68];
    __shared__ float lg[16][17];

    int tid = threadIdx.x;
    int t = tid >> 4, e = tid & 15;
    int srow = tid >> 4, scol = (tid & 15) * 4;   // staging: one float4/thread

    float acc = 0.f;
    for (int k0 = 0; k0 < DIM; k0 += 64) {
        *(float4*)&xs[srow][scol] = *(const float4*)&x[(size_t)(tb + srow) * DIM + k0 + scol];
        *(float4*)&rs[srow][scol] = *(const float4*)&rw[(size_t)srow * DIM + k0 + scol];
        __syncthreads();
        const float2* xp = (const float2*)xs[t];
        const float2* rp = (const float2*)rs[e];
        #pragma unroll
        for (int k = 0; k < 32; k++) {
            float2 a = xp[k], b = rp[k];
            acc = fmaf(a.x, b.x, acc);
            acc = fmaf(a.y, b.y, acc);
        }
        __syncthreads();
    }
    lg[t][e] = acc;
    __syncthreads();

    if (tid < 16) {
        int n = tb + tid;
        float v0 = -3.402823466e+38f, v1 = -3.402823466e+38f;
        int i0 = 0, i1 = 0;
        #pragma unroll
        for (int ee = 0; ee < NEXP; ee++) {
            float v = lg[tid][ee];
            if (v > v0) { v1 = v0; i1 = i0; v0 = v; i0 = ee; }
            else if (v > v1) { v1 = v; i1 = ee; }
        }
        float e1 = expf(v1 - v0);
        float inv = 1.f / (1.f + e1);
        idx[2 * n] = i0; idx[2 * n + 1] = i1;
        gate[2 * n] = inv; gate[2 * n + 1] = e1 * inv;
    }
}

// ---- Plan: counts/gsum -> offsets + aux + worklist + scatter (one block) ----
__global__ __launch_bounds__(256)
void plan_kernel(const int* __restrict__ idx, const float* __restrict__ gate,
                 int* __restrict__ offsets, int* __restrict__ tlist,
                 int* __restrict__ wl, int* __restrict__ wcount,
                 float* __restrict__ aux_out) {
    __shared__ int cnt_s[16];
    __shared__ float gs_s[16];
    __shared__ int pos_s[16];
    __shared__ int offs_s[17];
    int tid = threadIdx.x;
    if (tid < 16) { cnt_s[tid] = 0; gs_s[tid] = 0.f; pos_s[tid] = 0; }
    __syncthreads();
    for (int i = tid; i < NASSIGN; i += 256) {
        int e = idx[i];
        atomicAdd(&cnt_s[e], 1);
        atomicAdd(&gs_s[e], gate[i]);
    }
    __syncthreads();
    if (tid == 0) {
        int acc = 0;
        for (int e = 0; e < NEXP; e++) { offs_s[e] = acc; acc += cnt_s[e]; }
        offs_s[NEXP] = acc;
        float tot = (float)acc;
        float s = 0.f;
        for (int e = 0; e < NEXP; e++) {
            float c = (float)cnt_s[e];
            s += (c / tot) * (gs_s[e] / fmaxf(c, 1.f));
        }
        *aux_out = 0.02f * (s / (float)NEXP);
        int m = 0;
        for (int e = 0; e < NEXP; e++) {
            int nt = (cnt_s[e] + 127) >> 7;
            for (int rt = 0; rt < nt; rt++) wl[m++] = (e << 8) | rt;
        }
        *wcount = m;
    }
    __syncthreads();
    if (tid < 17) offsets[tid] = offs_s[tid];
    for (int i = tid; i < NASSIGN; i += 256) {
        int e = idx[i];
        int p = atomicAdd(&pos_s[e], 1);
        tlist[offs_s[e] + p] = i;
    }
}

__device__ __forceinline__ float gelu_tanh(float v) {
    float v3 = v * v * v;
    float t = tanhf(0.7978845608028654f * (v + 0.044715f * v3));
    return 0.5f * v * (1.f + t);
}

// =====================================================================
// MFMA grouped GEMM, 128x128 tile, BK=32 bf16, 4 waves (each 64x64).
// Dense worklist grid + XOR-swizzled LDS (2-way banks, free).
// =====================================================================

// GEMM1: h[a, :] = gelu(x[tok(a)] @ w1[e]^T + b1[e]),  K=DIM=1024, N=HID=1536
__global__ __launch_bounds__(256)
void gemm1_kernel(const u16* __restrict__ xb, const u16* __restrict__ w1b,
                  const float* __restrict__ b1,
                  const int* __restrict__ offsets, const int* __restrict__ tlist,
                  const int* __restrict__ wl, const int* __restrict__ wcount,
                  u16* __restrict__ h_bf) {
    int bid = blockIdx.x;
    int item = bid / 12;
    if (item >= *wcount) return;
    int colt = bid - item * 12;
    int w = wl[item];
    int e = w >> 8, rt = w & 255;
    int beg = offsets[e], ne = offsets[e + 1] - beg;
    int row0 = rt * 128, col0 = colt * 128;

    __shared__ u16 As[128 * 32];
    __shared__ u16 Bs[128 * 32];

    int tid = threadIdx.x;
    int wave = tid >> 6, lane = tid & 63;
    int wm = wave & 1, wn = wave >> 1;

    int koff = (((lane & 3) ^ ((lane >> 3) & 3)) * 8);
    const u16* aptr[2];
    const u16* bptr[2];
    #pragma unroll
    for (int q = 0; q < 2; q++) {
        int lrow = wave * 32 + q * 16 + (lane >> 2);
        int gi = beg + row0 + lrow;
        int gi2 = (row0 + lrow < ne) ? gi : beg;     // clamp OOB rows to a valid row
        int tok = tlist[gi2] >> 1;
        aptr[q] = xb + (size_t)tok * DIM + koff;
        int n = col0 + lrow;                          // B row = output col, always < HID
        bptr[q] = w1b + (size_t)(e * HID + n) * DIM + koff;
    }

    int rchunk = (((lane >> 4) ^ ((lane >> 1) & 3)) * 8);

    floatx4 acc[4][4] = {};
    for (int k0 = 0; k0 < DIM; k0 += 32) {
        #pragma unroll
        for (int q = 0; q < 2; q++) {
            GLOAD_LDS16(aptr[q] + k0, &As[(wave * 32 + q * 16) * 32]);
            GLOAD_LDS16(bptr[q] + k0, &Bs[(wave * 32 + q * 16) * 32]);
        }
        __syncthreads();
        short8 af[4], bf_[4];
        #pragma unroll
        for (int mi = 0; mi < 4; mi++)
            af[mi] = *(const short8*)&As[(wm * 64 + mi * 16 + (lane & 15)) * 32 + rchunk];
        #pragma unroll
        for (int nj = 0; nj < 4; nj++)
            bf_[nj] = *(const short8*)&Bs[(wn * 64 + nj * 16 + (lane & 15)) * 32 + rchunk];
        #pragma unroll
        for (int mi = 0; mi < 4; mi++)
            #pragma unroll
            for (int nj = 0; nj < 4; nj++)
                acc[mi][nj] = __builtin_amdgcn_mfma_f32_16x16x32_bf16(af[mi], bf_[nj], acc[mi][nj], 0, 0, 0);
        __syncthreads();
    }

    #pragma unroll
    for (int mi = 0; mi < 4; mi++) {
        #pragma unroll
        for (int r = 0; r < 4; r++) {
            int lrow = wm * 64 + mi * 16 + (lane >> 4) * 4 + r;
            if (row0 + lrow >= ne) continue;
            size_t orow = (size_t)(beg + row0 + lrow);
            #pragma unroll
            for (int nj = 0; nj < 4; nj++) {
                int col = col0 + wn * 64 + nj * 16 + (lane & 15);
                float v = acc[mi][nj][r] + b1[e * HID + col];
                __hip_bfloat16 hb = __float2bfloat16(gelu_tanh(v));
                h_bf[orow * HID + col] = *(u16*)&hb;
            }
        }
    }
}

// GEMM2: out[tok(a)] += gate(a) * (h[a] @ w2[e]^T + b2[e]),  K=HID=1536, N=DIM=1024
__global__ __launch_bounds__(256)
void gemm2_kernel(const u16* __restrict__ h_bf, const u16* __restrict__ w2b,
                  const float* __restrict__ b2,
                  const int* __restrict__ offsets, const int* __restrict__ tlist,
                  const int* __restrict__ wl, const int* __restrict__ wcount,
                  const float* __restrict__ gate, float* __restrict__ out) {
    int bid = blockIdx.x;
    int item = bid >> 3;
    if (item >= *wcount) return;
    int colt = bid & 7;
    int w = wl[item];
    int e = w >> 8, rt = w & 255;
    int beg = offsets[e], ne = offsets[e + 1] - beg;
    int row0 = rt * 128, col0 = colt * 128;

    __shared__ u16 As[128 * 32];
    __shared__ u16 Bs[128 * 32];

    int tid = threadIdx.x;
    int wave = tid >> 6, lane = tid & 63;
    int wm = wave & 1, wn = wave >> 1;

    int koff = (((lane & 3) ^ ((lane >> 3) & 3)) * 8);
    const u16* aptr[2];
    const u16* bptr[2];
    #pragma unroll
    for (int q = 0; q < 2; q++) {
        int lrow = wave * 32 + q * 16 + (lane >> 2);
        int gi = beg + row0 + lrow;
        int gi2 = (row0 + lrow < ne) ? gi : beg;
        aptr[q] = h_bf + (size_t)gi2 * HID + koff;
        int n = col0 + lrow;                          // < DIM always
        bptr[q] = w2b + (size_t)(e * DIM + n) * HID + koff;
    }

    int rchunk = (((lane >> 4) ^ ((lane >> 1) & 3)) * 8);

    floatx4 acc[4][4] = {};
    for (int k0 = 0; k0 < HID; k0 += 32) {
        #pragma unroll
        for (int q = 0; q < 2; q++) {
            GLOAD_LDS16(aptr[q] + k0, &As[(wave * 32 + q * 16) * 32]);
            GLOAD_LDS16(bptr[q] + k0, &Bs[(wave * 32 + q * 16) * 32]);
        }
        __syncthreads();
        short8 af[4], bf_[4];
        #pragma unroll
        for (int mi = 0; mi < 4; mi++)
            af[mi] = *(const short8*)&As[(wm * 64 + mi * 16 + (lane & 15)) * 32 + rchunk];
        #pragma unroll
        for (int nj = 0; nj < 4; nj++)
            bf_[nj] = *(const short8*)&Bs[(wn * 64 + nj * 16 + (lane & 15)) * 32 + rchunk];
        #pragma unroll
        for (int mi = 0; mi < 4; mi++)
            #pragma unroll
            for (int nj = 0; nj < 4; nj++)
                acc[mi][nj] = __builtin_amdgcn_mfma_f32_16x16x32_bf16(af[mi], bf_[nj], acc[mi][nj], 0, 0, 0);
        __syncthreads();
    }

    #pragma unroll
    for (int mi = 0; mi < 4; mi++) {
        #pragma unroll
        for (int r = 0; r < 4; r++) {
            int lrow = wm * 64 + mi * 16 + (lane >> 4) * 4 + r;
            if (row0 + lrow >= ne) continue;
            int t = tlist[beg + row0 + lrow];
            float g = gate[t];
            int tok = t >> 1;
            #pragma unroll
            for (int nj = 0; nj < 4; nj++) {
                int col = col0 + wn * 64 + nj * 16 + (lane & 15);
                float v = g * (acc[mi][nj][r] + b2[e * DIM + col]);
                atomicAdd(&out[(size_t)tok * DIM + col], v);
            }
        }
    }
}

extern "C" void kernel_launch(void* const* d_in, const int* in_sizes, int n_in,
                              void* d_out, int out_size, void* d_ws, size_t ws_size,
                              hipStream_t stream) {
    const float* x  = (const float*)d_in[0];
    const float* rw = (const float*)d_in[1];
    const float* w1 = (const float*)d_in[2];
    const float* b1 = (const float*)d_in[3];
    const float* w2 = (const float*)d_in[4];
    const float* b2 = (const float*)d_in[5];
    float* out = (float*)d_out;   // fp32 output [N*D main | 1 aux]

    // ---- workspace layout (bytes) ----
    char* ws = (char*)d_ws;
    int*   offsets = (int*)(ws + 192);        // 17
    int*   wcount  = (int*)(ws + 384);        // 1
    int*   wl      = (int*)(ws + 512);        // up to 128
    int*   idx     = (int*)(ws + 4096);                               // 32 KB
    float* gate    = (float*)(ws + 4096 + 4 * NASSIGN);               // 32 KB
    int*   tlist   = (int*)(ws + 4096 + 8 * NASSIGN);                 // 32 KB
    u16*   x_bf    = (u16*)(ws + (128 << 10));                        // 8 MB
    u16*   h_bf    = x_bf + (size_t)N_TOK * DIM;                      // 25.2 MB
    u16*   w_bf    = h_bf + (size_t)NASSIGN * HID;                    // 50.3 MB (w1 then w2)

    hipMemsetAsync(d_out, 0, (size_t)out_size * 4, stream); // zero for atomic combine

    cvt_kernel<<<(N_TOK * DIM / 4 + 255) / 256, 256, 0, stream>>>(x, x_bf, N_TOK * DIM / 4);
    cvt_kernel<<<(NEXP * HID * DIM / 4 + 255) / 256, 256, 0, stream>>>(w1, w_bf, NEXP * HID * DIM / 4);

    logits_topk_kernel<<<N_TOK / 16, 256, 0, stream>>>(x, rw, idx, gate);
    plan_kernel<<<1, 256, 0, stream>>>(idx, gate, offsets, tlist, wl, wcount,
                                       out + (size_t)N_TOK * DIM);

    gemm1_kernel<<<MAX_ITEMS * 12, 256, 0, stream>>>(
        x_bf, w_bf, b1, offsets, tlist, wl, wcount, h_bf);

    cvt_kernel<<<(NEXP * DIM * HID / 4 + 255) / 256, 256, 0, stream>>>(w2, w_bf, NEXP * DIM * HID / 4);

    gemm2_kernel<<<MAX_ITEMS * 8, 256, 0, stream>>>(
        h_bf, w_bf, b2, offsets, tlist, wl, wcount, gate, out);
}